// Round 2
// baseline (775.480 us; speedup 1.0000x reference)
//
#include <hip/hip_runtime.h>

typedef short v8s __attribute__((ext_vector_type(8)));
typedef float v4f __attribute__((ext_vector_type(4)));

// problem constants
#define NBATCH 16
#define NCH    64
#define NHH    128
#define NWW    128
#define NEXP   8
#define NOC    64
#define KSTEPS 18          // 576 / 32

// LDS slab layout: [4 rows][66 cols][72 c (64 + 8 pad)] bf16
#define CSTR 72
#define COLS 66

__device__ __forceinline__ unsigned short f2bf(float f) {
  unsigned int u = __float_as_uint(f);
  u += 0x7FFFu + ((u >> 16) & 1u);           // round-to-nearest-even
  return (unsigned short)(u >> 16);
}

// ---------------------------------------------------------------------------
// Pack expert weights into MFMA B-fragment-linear bf16:
// element (((e*18+s)*4+nt)*64+lane)*8+j  =  W[k = s*32+(lane>>4)*8+j][n = nt*16+(lane&15)]
// with k = (kh*3+kw)*64 + c  and W[k][n] = expert_w[e][n][c][kh][kw]
// Total elements: 8*18*4*64*8 = 294912  (one bf16 each)
// ---------------------------------------------------------------------------
__global__ void pack_b_kernel(const float* __restrict__ ew,
                              unsigned short* __restrict__ bp) {
  int f = blockIdx.x * 256 + threadIdx.x;    // 0 .. 294911
  int j = f & 7;
  int t = f >> 3;
  int lane = t & 63;
  t >>= 6;
  int nt = t & 3;
  t >>= 2;                                   // t = e*18 + s, 0..143
  int s = t % KSTEPS;
  int e = t / KSTEPS;
  int k = s * 32 + (lane >> 4) * 8 + j;
  int n = nt * 16 + (lane & 15);
  int khw = k >> 6;
  int c = k & 63;
  bp[f] = f2bf(ew[((e * NOC + n) * NCH + c) * 9 + khw]);
}

// ---------------------------------------------------------------------------
// Gating: one block per patch (b, ph, pw). fp32 dot + softmax.
// ---------------------------------------------------------------------------
__global__ void gate_kernel(const float* __restrict__ x,
                            const float* __restrict__ gw,
                            const float* __restrict__ gb,
                            float* __restrict__ gate_out) {
  int pid = blockIdx.x;
  int pw = pid & 15;
  int ph = (pid >> 4) & 15;
  int b  = pid >> 8;
  int tid = threadIdx.x;

  float cy = (ph + 0.5f) / 16.0f;
  float cx = (pw + 0.5f) / 16.0f;

  float acc[8];
#pragma unroll
  for (int e = 0; e < 8; ++e) acc[e] = 0.f;

  for (int idx = tid; idx < 6144; idx += 256) {
    int ch = idx >> 6;
    int pix = idx & 63;
    float v;
    if (ch < 64) {
      v = x[((b * NCH + ch) * NHH + ph * 8 + (pix >> 3)) * NWW + pw * 8 + (pix & 7)];
    } else {
      int j = ch - 64;
      float freq = (float)(1 << (j & 7)) * 3.14159265358979323846f;
      float base = (j < 16) ? cy : cx;
      float a = base * freq;
      v = ((j >> 3) & 1) ? cosf(a) : sinf(a);
    }
#pragma unroll
    for (int e = 0; e < 8; ++e) acc[e] += v * gw[e * 6144 + idx];
  }

#pragma unroll
  for (int e = 0; e < 8; ++e)
    for (int off = 32; off > 0; off >>= 1)
      acc[e] += __shfl_down(acc[e], off, 64);

  __shared__ float red[8][4];
  int wid = tid >> 6;
  int lane = tid & 63;
  if (lane == 0) {
#pragma unroll
    for (int e = 0; e < 8; ++e) red[e][wid] = acc[e];
  }
  __syncthreads();
  if (tid == 0) {
    float lg[8];
    float mx = -1e30f;
#pragma unroll
    for (int e = 0; e < 8; ++e) {
      lg[e] = red[e][0] + red[e][1] + red[e][2] + red[e][3] + gb[e];
      mx = fmaxf(mx, lg[e]);
    }
    float sum = 0.f;
#pragma unroll
    for (int e = 0; e < 8; ++e) { lg[e] = expf(lg[e] - mx); sum += lg[e]; }
    float inv = 1.0f / sum;
#pragma unroll
    for (int e = 0; e < 8; ++e) gate_out[pid * 8 + e] = lg[e] * inv;
  }
}

// ---------------------------------------------------------------------------
// Main fused kernel: block = 2 waves; wave w handles output row h = hp*2+w,
// cols w0..w0+63, all 64 oc, all 8 experts (gated accumulate in regs).
// ---------------------------------------------------------------------------
__global__ __launch_bounds__(128, 2) void moe_conv_kernel(
    const float* __restrict__ x,
    const float* __restrict__ eb,
    const unsigned short* __restrict__ bp,
    const float* __restrict__ gate,
    float* __restrict__ out) {
  __shared__ __align__(16) unsigned short slab[4 * COLS * CSTR];  // 38016 B
  __shared__ float ldsg[64];                                      // [pw_local 8][e 8]

  const int tid = threadIdx.x;
  const int bid = blockIdx.x;
  const int wseg = bid & 1;
  const int hp = (bid >> 1) & 63;
  const int b = bid >> 7;
  const int w0 = wseg * 64;
  const int wid = tid >> 6;
  const int lane = tid & 63;
  const int quad = lane >> 4;
  const int l15 = lane & 15;

  // gates for this row-pair's 8 patches
  if (tid < 64) {
    int ph = hp >> 2;
    int pw0 = w0 >> 3;
    ldsg[tid] = gate[((b * 16 + ph) * 16 + pw0 + (tid >> 3)) * 8 + (tid & 7)];
  }

  // stage x slab: rows hp*2-1 .. hp*2+2, cols w0-1 .. w0+64, all c (bf16)
  const int hbase = hp * 2 - 1;
  const int wbase = w0 - 1;
  for (int flat = tid; flat < 4 * 32 * 66; flat += 128) {
    int col = flat % 66;
    int t = flat / 66;
    int cp = t & 31;                    // channel pair
    int r = t >> 5;                     // slab row
    int gh = hbase + r;
    int gw_ = wbase + col;
    float v0 = 0.f, v1 = 0.f;
    if (((unsigned)gh < 128u) && ((unsigned)gw_ < 128u)) {
      const float* px = x + (((b * NCH + cp * 2) * NHH + gh) * NWW + gw_);
      v0 = px[0];
      v1 = px[NHH * NWW];
    }
    unsigned int pk = (unsigned int)f2bf(v0) | ((unsigned int)f2bf(v1) << 16);
    *(unsigned int*)&slab[(r * 66 + col) * CSTR + cp * 2] = pk;
  }
  __syncthreads();

  const v4f vzero = {0.f, 0.f, 0.f, 0.f};
  v4f oacc[4][4];
#pragma unroll
  for (int mt = 0; mt < 4; ++mt)
#pragma unroll
    for (int nt = 0; nt < 4; ++nt) oacc[mt][nt] = vzero;

  for (int e = 0; e < 8; ++e) {
    v4f vacc[4][4];
#pragma unroll
    for (int mt = 0; mt < 4; ++mt)
#pragma unroll
      for (int nt = 0; nt < 4; ++nt) vacc[mt][nt] = vzero;

    int sidx = 0;
    for (int kh = 0; kh < 3; ++kh) {
      for (int kw = 0; kw < 3; ++kw) {
        const unsigned short* arow = &slab[((wid + kh) * 66 + l15 + kw) * CSTR];
#pragma unroll
        for (int ch = 0; ch < 2; ++ch, ++sidx) {
          // B fragments: one coalesced 16B load per lane per n-tile
          v8s bf[4];
          const v8s* bsrc = (const v8s*)bp + ((e * KSTEPS + sidx) * 4) * 64 + lane;
#pragma unroll
          for (int nt = 0; nt < 4; ++nt) bf[nt] = bsrc[nt * 64];
          // A fragments: sliding-window ds_read_b128
          const unsigned short* abase = arow + ch * 32 + quad * 8;
          v8s af[4];
#pragma unroll
          for (int mt = 0; mt < 4; ++mt)
            af[mt] = *(const v8s*)(abase + mt * 16 * CSTR);
#pragma unroll
          for (int mt = 0; mt < 4; ++mt)
#pragma unroll
            for (int nt = 0; nt < 4; ++nt)
              vacc[mt][nt] = __builtin_amdgcn_mfma_f32_16x16x32_bf16(
                  af[mt], bf[nt], vacc[mt][nt], 0, 0, 0);
        }
      }
    }

    // epilogue: bias + relu + gate, accumulate
    float bias[4];
#pragma unroll
    for (int nt = 0; nt < 4; ++nt) bias[nt] = eb[e * NOC + nt * 16 + l15];
#pragma unroll
    for (int mt = 0; mt < 4; ++mt) {
      float g = ldsg[(mt * 2 + (quad >> 1)) * 8 + e];
#pragma unroll
      for (int nt = 0; nt < 4; ++nt) {
#pragma unroll
        for (int r = 0; r < 4; ++r) {
          float v = vacc[mt][nt][r] + bias[nt];
          v = fmaxf(v, 0.f);
          oacc[mt][nt][r] += v * g;
        }
      }
    }
  }

  // transpose through LDS for coalesced NCHW stores
  __syncthreads();                       // all waves done reading slab
  float* tb = (float*)slab + wid * (64 * 68);
#pragma unroll
  for (int mt = 0; mt < 4; ++mt)
#pragma unroll
    for (int nt = 0; nt < 4; ++nt)
#pragma unroll
      for (int r = 0; r < 4; ++r)
        tb[(nt * 16 + l15) * 68 + mt * 16 + quad * 4 + r] = oacc[mt][nt][r];
  __syncthreads();

  const int h = hp * 2 + wid;
  float* orow = out + ((b * NOC) * NHH + h) * NWW + w0;
#pragma unroll
  for (int g4 = 0; g4 < 16; ++g4) {
    int oc = g4 * 4 + quad;
    v4f vv = *(const v4f*)(tb + oc * 68 + l15 * 4);
    *(v4f*)(orow + oc * (NHH * NWW) + l15 * 4) = vv;
  }
}

// ---------------------------------------------------------------------------
extern "C" void kernel_launch(void* const* d_in, const int* in_sizes, int n_in,
                              void* d_out, int out_size, void* d_ws, size_t ws_size,
                              hipStream_t stream) {
  const float* x  = (const float*)d_in[0];
  const float* ew = (const float*)d_in[1];
  const float* eb = (const float*)d_in[2];
  const float* gw = (const float*)d_in[3];
  const float* gb = (const float*)d_in[4];
  float* out = (float*)d_out;

  unsigned short* bp = (unsigned short*)d_ws;              // 294912 bf16 = 589824 B
  float* gate = (float*)((char*)d_ws + 589824);            // 4096*8 fp32 = 131072 B

  hipLaunchKernelGGL(pack_b_kernel, dim3(1152), dim3(256), 0, stream, ew, bp);
  hipLaunchKernelGGL(gate_kernel, dim3(4096), dim3(256), 0, stream, x, gw, gb, gate);
  hipLaunchKernelGGL(moe_conv_kernel, dim3(2048), dim3(128), 0, stream, x, eb, bp, gate, out);
}